// Round 3
// baseline (460.516 us; speedup 1.0000x reference)
//
#include <hip/hip_runtime.h>
#include <hip/hip_bf16.h>

// GCN 7-layer forward on MI355X. R3:
//  - sharded LDS degree histogram (removes 1.28M memory-side atomics = 56us)
//  - split-bf16 (hi+lo) MFMA GEMMs, fp32 accum: D += Ah*Bh + Ah*Bl + Al*Bh
//    (agg epilogues emit hi/lo bf16 planes; gather stays fp32)

#define IN_F 128

typedef __attribute__((ext_vector_type(8))) short short8v;   // 8 bf16 = 4 VGPRs
typedef __attribute__((ext_vector_type(4))) float f32x4;

static __device__ __forceinline__ unsigned short f2bf(float x) {
    unsigned u = __builtin_bit_cast(unsigned, x);
    unsigned r = (u + 0x7FFFu + ((u >> 16) & 1u)) >> 16;   // rn-even
    return (unsigned short)r;
}
static __device__ __forceinline__ float bf2f(unsigned short h) {
    unsigned u = ((unsigned)h) << 16;
    return __builtin_bit_cast(float, u);
}

// ---------------- sharded LDS histogram for degrees ----------------
// SHB=12 (4096 nodes/shard), S=10 shards, B=16 edge slices. 32 KB LDS/block.

template<int SHB, int B>
__global__ __launch_bounds__(256) void hist_kernel(const int* __restrict__ src,
                                                   const int* __restrict__ dst,
                                                   int* __restrict__ scratch,
                                                   int E, int SBtot) {
    constexpr int SH = 1 << SHB;
    __shared__ int ho[SH];
    __shared__ int hin[SH];
    const int t = threadIdx.x;
    const int b = blockIdx.x;   // edge slice
    const int s = blockIdx.y;   // node shard
    for (int i = t; i < SH; i += 256) { ho[i] = 0; hin[i] = 0; }
    __syncthreads();
    const int per = (E + B - 1) / B;
    const int lo = b * per;
    const int hiE = min(lo + per, E);
    const int base = s << SHB;
    for (int e = lo + t; e < hiE; e += 256) {
        unsigned a = (unsigned)(src[e] - base);
        if (a < (unsigned)SH) atomicAdd(&ho[a], 1);
        unsigned c = (unsigned)(dst[e] - base);
        if (c < (unsigned)SH) atomicAdd(&hin[c], 1);
    }
    __syncthreads();
    const int blk = s * B + b;
    int* so = scratch + (size_t)blk * SH;
    int* si = scratch + ((size_t)(SBtot + blk)) * SH;
    for (int i = t; i < SH; i += 256) { so[i] = ho[i]; si[i] = hin[i]; }
}

template<int SHB, int B>
__global__ void hist_reduce_kernel(const int* __restrict__ scratch,
                                   int* __restrict__ in_deg,
                                   float* __restrict__ out_nrm,
                                   float* __restrict__ in_nrm, int N, int SBtot) {
    constexpr int SH = 1 << SHB;
    int n = blockIdx.x * blockDim.x + threadIdx.x;
    if (n >= N) return;
    int s = n >> SHB;
    int i = n & (SH - 1);
    int od = 0, idg = 0;
    for (int b = 0; b < B; ++b) {
        int blk = s * B + b;
        od  += scratch[(size_t)blk * SH + i];
        idg += scratch[((size_t)(SBtot + blk)) * SH + i];
    }
    in_deg[n] = idg;
    out_nrm[n] = od  > 0 ? rsqrtf((float)od)  : 0.f;
    in_nrm[n]  = idg > 0 ? rsqrtf((float)idg) : 0.f;
}

// ---------------- multi-block exclusive scan of in_deg -> row_off ----------------

__global__ __launch_bounds__(256) void scan_blk_kernel(const int* __restrict__ deg,
                                                       int* __restrict__ blockSums, int N) {
    __shared__ int ws[4];
    const int t = threadIdx.x;
    const int base = blockIdx.x * 1024 + t * 4;
    int4 v = make_int4(0, 0, 0, 0);
    if (base + 3 < N) v = *reinterpret_cast<const int4*>(&deg[base]);
    else if (base < N) {
        v.x = deg[base];
        if (base + 1 < N) v.y = deg[base + 1];
        if (base + 2 < N) v.z = deg[base + 2];
    }
    int s = v.x + v.y + v.z + v.w;
#pragma unroll
    for (int off = 32; off > 0; off >>= 1) s += __shfl_down(s, off);
    if ((t & 63) == 0) ws[t >> 6] = s;
    __syncthreads();
    if (t == 0) blockSums[blockIdx.x] = ws[0] + ws[1] + ws[2] + ws[3];
}

__global__ __launch_bounds__(64) void scan_top_kernel(const int* __restrict__ blockSums,
                                                      int* __restrict__ blockOffs,
                                                      int* __restrict__ row_off, int NB, int N) {
    const int t = threadIdx.x;
    int orig = (t < NB) ? blockSums[t] : 0;
    int v = orig;
#pragma unroll
    for (int off = 1; off < 64; off <<= 1) {
        int u = __shfl_up(v, off);
        if (t >= off) v += u;
    }
    if (t < NB) blockOffs[t] = v - orig;
    if (t == 63) row_off[N] = v;
}

__global__ __launch_bounds__(256) void scan_fill_kernel(const int* __restrict__ deg,
                                                        const int* __restrict__ blockOffs,
                                                        int* __restrict__ row_off,
                                                        int* __restrict__ cursor, int N) {
    __shared__ int wtot[4];
    const int t = threadIdx.x;
    const int lane = t & 63;
    const int wid = t >> 6;
    const int base = blockIdx.x * 1024 + t * 4;
    int4 v = make_int4(0, 0, 0, 0);
    if (base + 3 < N) v = *reinterpret_cast<const int4*>(&deg[base]);
    else if (base < N) {
        v.x = deg[base];
        if (base + 1 < N) v.y = deg[base + 1];
        if (base + 2 < N) v.z = deg[base + 2];
    }
    const int s = v.x + v.y + v.z + v.w;
    int incl = s;
#pragma unroll
    for (int off = 1; off < 64; off <<= 1) {
        int u = __shfl_up(incl, off);
        if (lane >= off) incl += u;
    }
    if (lane == 63) wtot[wid] = incl;
    __syncthreads();
    int pre = blockOffs[blockIdx.x] + incl - s;
    for (int i = 0; i < wid; ++i) pre += wtot[i];
    if (base < N) {
        int run = pre;
        row_off[base] = run; cursor[base] = run; run += v.x;
        if (base + 1 < N) { row_off[base + 1] = run; cursor[base + 1] = run; run += v.y; }
        if (base + 2 < N) { row_off[base + 2] = run; cursor[base + 2] = run; run += v.z; }
        if (base + 3 < N) { row_off[base + 3] = run; cursor[base + 3] = run; }
    }
}

__global__ void fill_kernel(const int* __restrict__ src, const int* __restrict__ dst,
                            int* __restrict__ cursor, int* __restrict__ csr, int E) {
    int e = blockIdx.x * blockDim.x + threadIdx.x;
    if (e < E) {
        int pos = atomicAdd(&cursor[dst[e]], 1);
        csr[pos] = src[e];
    }
}

// ---------------- split conversions ----------------

// fh/fl = split(in_feat * out_nrm[row]), rows of 128
__global__ void split_feat_kernel(const float* __restrict__ x, const float* __restrict__ snrm,
                                  unsigned short* __restrict__ th, unsigned short* __restrict__ tl,
                                  int total4) {
    int i = blockIdx.x * blockDim.x + threadIdx.x;
    if (i >= total4) return;
    float4 v = reinterpret_cast<const float4*>(x)[i];
    float sc = snrm[i >> 5];   // (i*4)/128
    ushort4 h, l;
    float a;
    a = v.x * sc; h.x = f2bf(a); l.x = f2bf(a - bf2f(h.x));
    a = v.y * sc; h.y = f2bf(a); l.y = f2bf(a - bf2f(h.y));
    a = v.z * sc; h.z = f2bf(a); l.z = f2bf(a - bf2f(h.z));
    a = v.w * sc; h.w = f2bf(a); l.w = f2bf(a - bf2f(h.w));
    reinterpret_cast<ushort4*>(th)[i] = h;
    reinterpret_cast<ushort4*>(tl)[i] = l;
}

struct WDesc { const float* w; unsigned short* th; unsigned short* tl; int K; int N; };
struct WPack { WDesc d[6]; };

// transpose W[K][N] -> Wt[N][K] hi/lo planes; one block per weight
__global__ void split_w_kernel(WPack p) {
    WDesc d = p.d[blockIdx.x];
    int total = d.K * d.N;
    for (int i = threadIdx.x; i < total; i += blockDim.x) {
        int k = i / d.N, n = i - k * d.N;
        float v = d.w[i];
        unsigned short h = f2bf(v);
        d.th[(size_t)n * d.K + k] = h;
        d.tl[(size_t)n * d.K + k] = f2bf(v - bf2f(h));
    }
}

// ---------------- MFMA GEMM: Y = A @ Wt^T with split-bf16 operands ----------------
// A planes [M][K] bf16 hi/lo; Wt planes [NOUT][K]. 4 waves/block, 16 rows/wave.
// epilogue: (acc*r + bias)? relu? *s?; out fp32 or split-bf16 planes.

template<int K, int NOUT, bool POST, bool RELU, bool POST2, bool SPLIT>
__global__ __launch_bounds__(256) void gemm_mfma(
    const unsigned short* __restrict__ Ah, const unsigned short* __restrict__ Al,
    const unsigned short* __restrict__ Bh, const unsigned short* __restrict__ Bl,
    const float* __restrict__ r_nrm, const float* __restrict__ s_nrm,
    const float* __restrict__ bias,
    float* __restrict__ Yf, unsigned short* __restrict__ Yh, unsigned short* __restrict__ Yl,
    int M) {
    constexpr int NT = NOUT / 16;
    const int lane = threadIdx.x & 63;
    const int wv = threadIdx.x >> 6;
    const int r0 = blockIdx.x * 64 + wv * 16;
    const int arow = r0 + (lane & 15);
    const int kg = (lane >> 4) * 8;

    f32x4 acc[NT];
#pragma unroll
    for (int n = 0; n < NT; ++n) acc[n] = (f32x4){0.f, 0.f, 0.f, 0.f};

    for (int kk = 0; kk < K; kk += 32) {
        short8v a_h = *reinterpret_cast<const short8v*>(Ah + (size_t)arow * K + kk + kg);
        short8v a_l = *reinterpret_cast<const short8v*>(Al + (size_t)arow * K + kk + kg);
#pragma unroll
        for (int n = 0; n < NT; ++n) {
            int col = n * 16 + (lane & 15);
            short8v b_h = *reinterpret_cast<const short8v*>(Bh + (size_t)col * K + kk + kg);
            short8v b_l = *reinterpret_cast<const short8v*>(Bl + (size_t)col * K + kk + kg);
            acc[n] = __builtin_amdgcn_mfma_f32_16x16x32_bf16(a_h, b_h, acc[n], 0, 0, 0);
            acc[n] = __builtin_amdgcn_mfma_f32_16x16x32_bf16(a_h, b_l, acc[n], 0, 0, 0);
            acc[n] = __builtin_amdgcn_mfma_f32_16x16x32_bf16(a_l, b_h, acc[n], 0, 0, 0);
        }
    }

    const int c0 = lane & 15;
    const int rr = r0 + (lane >> 4) * 4;
#pragma unroll
    for (int n = 0; n < NT; ++n) {
        const int col = n * 16 + c0;
        const float bcol = POST ? bias[col] : 0.f;
#pragma unroll
        for (int j = 0; j < 4; ++j) {
            const int row = rr + j;
            float y = acc[n][j];
            if (POST) y = fmaf(y, r_nrm[row], bcol);
            if (RELU) y = fmaxf(y, 0.f);
            if (POST2) y *= s_nrm[row];
            if (SPLIT) {
                unsigned short h = f2bf(y);
                Yh[(size_t)row * NOUT + col] = h;
                Yl[(size_t)row * NOUT + col] = f2bf(y - bf2f(h));
            } else {
                Yf[(size_t)row * NOUT + col] = y;
            }
        }
    }
}

// ---------------- float4 CSR aggregation; out fp32 or split-bf16 ----------------

template<int F, bool POST, bool RELU, bool POST2, bool SPLIT>
__global__ __launch_bounds__(256) void agg4_kernel(
    const float* __restrict__ X, const int* __restrict__ csr,
    const int* __restrict__ row_off, const float* __restrict__ r_nrm,
    const float* __restrict__ s_nrm, const float* __restrict__ bias,
    float* __restrict__ Yf, unsigned short* __restrict__ Yh, unsigned short* __restrict__ Yl,
    int N) {
    constexpr int LPE = F / 4;
    constexpr int EPW = 64 / LPE;
    const int lane = threadIdx.x & 63;
    const int node = blockIdx.x * (blockDim.x >> 6) + (threadIdx.x >> 6);
    if (node >= N) return;
    const int g = lane / LPE;
    const int c = lane % LPE;
    const int lo = row_off[node];
    const int hi = row_off[node + 1];
    float4 acc = make_float4(0.f, 0.f, 0.f, 0.f);
    for (int e = lo + g; e < hi; e += EPW) {
        int s = csr[e];
        const float4 x = *reinterpret_cast<const float4*>(&X[(size_t)s * F + c * 4]);
        acc.x += x.x; acc.y += x.y; acc.z += x.z; acc.w += x.w;
    }
#pragma unroll
    for (int m = 32; m >= LPE; m >>= 1) {
        acc.x += __shfl_xor(acc.x, m);
        acc.y += __shfl_xor(acc.y, m);
        acc.z += __shfl_xor(acc.z, m);
        acc.w += __shfl_xor(acc.w, m);
    }
    if (lane < LPE) {
        float4 o = acc;
        if (POST) {
            float rn = r_nrm[node];
            const float4 b = *reinterpret_cast<const float4*>(&bias[c * 4]);
            o.x = fmaf(o.x, rn, b.x);
            o.y = fmaf(o.y, rn, b.y);
            o.z = fmaf(o.z, rn, b.z);
            o.w = fmaf(o.w, rn, b.w);
        }
        if (RELU) {
            o.x = fmaxf(o.x, 0.f); o.y = fmaxf(o.y, 0.f);
            o.z = fmaxf(o.z, 0.f); o.w = fmaxf(o.w, 0.f);
        }
        if (POST2) {
            float sn = s_nrm[node];
            o.x *= sn; o.y *= sn; o.z *= sn; o.w *= sn;
        }
        if (SPLIT) {
            ushort4 h, l;
            h.x = f2bf(o.x); l.x = f2bf(o.x - bf2f(h.x));
            h.y = f2bf(o.y); l.y = f2bf(o.y - bf2f(h.y));
            h.z = f2bf(o.z); l.z = f2bf(o.z - bf2f(h.z));
            h.w = f2bf(o.w); l.w = f2bf(o.w - bf2f(h.w));
            *reinterpret_cast<ushort4*>(&Yh[(size_t)node * F + c * 4]) = h;
            *reinterpret_cast<ushort4*>(&Yl[(size_t)node * F + c * 4]) = l;
        } else {
            *reinterpret_cast<float4*>(&Yf[(size_t)node * F + c * 4]) = o;
        }
    }
}

// ---------------- layer 7 ----------------

__global__ __launch_bounds__(256) void gemv64_kernel(const float* __restrict__ X,
                                                     const float* __restrict__ W,
                                                     float* __restrict__ Y, int M) {
    const int lane = threadIdx.x & 63;
    const int m = blockIdx.x * (blockDim.x >> 6) + (threadIdx.x >> 6);
    if (m >= M) return;
    float v = X[(size_t)m * 64 + lane] * W[lane];
#pragma unroll
    for (int off = 32; off > 0; off >>= 1) v += __shfl_down(v, off);
    if (lane == 0) Y[m] = v;
}

__global__ __launch_bounds__(256) void agg1_kernel(const float* __restrict__ T,
                                                   const int* __restrict__ csr,
                                                   const int* __restrict__ row_off,
                                                   const float* __restrict__ r_nrm,
                                                   const float* __restrict__ bias,
                                                   float* __restrict__ Y, int N) {
    const int node = blockIdx.x * 16 + (threadIdx.x >> 4);
    const int l = threadIdx.x & 15;
    if (node >= N) return;
    const int lo = row_off[node];
    const int hi = row_off[node + 1];
    float acc = 0.f;
    for (int e = lo + l; e < hi; e += 16) acc += T[csr[e]];
#pragma unroll
    for (int m = 8; m >= 1; m >>= 1) acc += __shfl_xor(acc, m);
    if (l == 0) Y[node] = fmaf(acc, r_nrm[node], bias[0]);
}

// ---------------- host ----------------

extern "C" void kernel_launch(void* const* d_in, const int* in_sizes, int n_in,
                              void* d_out, int out_size, void* d_ws, size_t ws_size,
                              hipStream_t stream) {
    const float* in_feat = (const float*)d_in[0];
    const int* src = (const int*)d_in[1];
    const int* dst = (const int*)d_in[2];
    const float* W1 = (const float*)d_in[3];  const float* B1 = (const float*)d_in[4];
    const float* W2 = (const float*)d_in[5];  const float* B2 = (const float*)d_in[6];
    const float* W3 = (const float*)d_in[7];  const float* B3 = (const float*)d_in[8];
    const float* W4 = (const float*)d_in[9];  const float* B4 = (const float*)d_in[10];
    const float* W5 = (const float*)d_in[11]; const float* B5 = (const float*)d_in[12];
    const float* W6 = (const float*)d_in[13]; const float* B6 = (const float*)d_in[14];
    const float* W7 = (const float*)d_in[15]; const float* B7 = (const float*)d_in[16];

    const int N = in_sizes[0] / IN_F;   // 40000
    const int E = in_sizes[1];          // 640000
    float* out = (float*)d_out;

    constexpr int SHB = 12;             // 4096 nodes/shard
    constexpr int HB = 16;              // edge slices
    const int S = (N + (1 << SHB) - 1) >> SHB;   // 10
    const int SBtot = S * HB;

    // workspace layout (16B aligned)
    char* w = (char*)d_ws;
    auto alloc = [&](size_t bytes) { char* p = w; w += (bytes + 255) & ~(size_t)255; return p; };
    int* csr      = (int*)alloc((size_t)E * 4);
    int* row_off  = (int*)alloc((size_t)(N + 1) * 4);
    int* cursor   = (int*)alloc((size_t)N * 4);
    int* in_deg   = (int*)alloc((size_t)N * 4);
    int* blockSums= (int*)alloc(64 * 4);
    int* blockOffs= (int*)alloc(64 * 4);
    float* out_nrm= (float*)alloc((size_t)N * 4);
    float* in_nrm = (float*)alloc((size_t)N * 4);
    // weight planes (transposed, hi/lo)
    const int dims[8] = {128, 64, 128, 128, 64, 64, 64, 1};
    unsigned short* wth[6]; unsigned short* wtl[6];
    for (int i = 0; i < 6; ++i) {
        size_t kn = (size_t)dims[i] * dims[i + 1];
        wth[i] = (unsigned short*)alloc(kn * 2);
        wtl[i] = (unsigned short*)alloc(kn * 2);
    }
    unsigned short* fh = (unsigned short*)alloc((size_t)N * 128 * 2);
    unsigned short* fl = (unsigned short*)alloc((size_t)N * 128 * 2);
    unsigned short* th = (unsigned short*)alloc((size_t)N * 128 * 2);
    unsigned short* tl = (unsigned short*)alloc((size_t)N * 128 * 2);
    float* bf0 = (float*)alloc((size_t)N * 128 * 4);
    float* bf1 = (float*)alloc((size_t)N * 128 * 4);
    int* scratch = (int*)bf0;   // hist scratch aliases bf0 (used before L1 gemm)
    (void)ws_size; (void)n_in; (void)out_size;

    const int TB = 256;
    const int NB = (N + 1023) / 1024;   // 40

    // weight split/transpose (independent)
    WPack wp;
    const float* Ws[6] = {W1, W2, W3, W4, W5, W6};
    for (int i = 0; i < 6; ++i) wp.d[i] = {Ws[i], wth[i], wtl[i], dims[i], dims[i + 1]};
    split_w_kernel<<<6, TB, 0, stream>>>(wp);

    // degrees + norms + CSR
    hist_kernel<SHB, HB><<<dim3(HB, S), TB, 0, stream>>>(src, dst, scratch, E, SBtot);
    hist_reduce_kernel<SHB, HB><<<(N + TB - 1) / TB, TB, 0, stream>>>(
        scratch, in_deg, out_nrm, in_nrm, N, SBtot);
    scan_blk_kernel<<<NB, TB, 0, stream>>>(in_deg, blockSums, N);
    scan_top_kernel<<<1, 64, 0, stream>>>(blockSums, blockOffs, row_off, NB, N);
    scan_fill_kernel<<<NB, TB, 0, stream>>>(in_deg, blockOffs, row_off, cursor, N);
    fill_kernel<<<(E + TB - 1) / TB, TB, 0, stream>>>(src, dst, cursor, csr, E);

    // input split (needs out_nrm)
    split_feat_kernel<<<(N * 32 + TB - 1) / TB, TB, 0, stream>>>(
        in_feat, out_nrm, fh, fl, N * 32);

    const int gridN4 = (N + 3) / 4;
    const int MB = N / 64;   // 625

    // L1: 128->64 mult-first. bf0 = t1 = split(x*s)@W1 ; bf1 = g1 = relu(agg(t1)*r+B1)*s
    gemm_mfma<128, 64, false, false, false, false><<<MB, TB, 0, stream>>>(
        fh, fl, wth[0], wtl[0], nullptr, nullptr, nullptr, bf0, nullptr, nullptr, N);
    agg4_kernel<64, true, true, true, false><<<gridN4, TB, 0, stream>>>(
        bf0, csr, row_off, in_nrm, out_nrm, B1, bf1, nullptr, nullptr, N);

    // L2: 64->128 agg-first. th/tl = t2 = agg(g1) ; bf0 = g2 = relu(t2@W2*r+B2)*s
    agg4_kernel<64, false, false, false, true><<<gridN4, TB, 0, stream>>>(
        bf1, csr, row_off, nullptr, nullptr, nullptr, nullptr, th, tl, N);
    gemm_mfma<64, 128, true, true, true, false><<<MB, TB, 0, stream>>>(
        th, tl, wth[1], wtl[1], in_nrm, out_nrm, B2, bf0, nullptr, nullptr, N);

    // L3: 128->128 agg-first. th/tl = t3 = agg(g2) ; fh/fl = g3 = split(relu(t3@W3*r+B3)*s)
    agg4_kernel<128, false, false, false, true><<<gridN4, TB, 0, stream>>>(
        bf0, csr, row_off, nullptr, nullptr, nullptr, nullptr, th, tl, N);
    gemm_mfma<128, 128, true, true, true, true><<<MB, TB, 0, stream>>>(
        th, tl, wth[2], wtl[2], in_nrm, out_nrm, B3, nullptr, fh, fl, N);

    // L4: 128->64 mult-first. bf0 = t4 = g3@W4 ; bf1 = g4 = relu(agg(t4)*r+B4)*s
    gemm_mfma<128, 64, false, false, false, false><<<MB, TB, 0, stream>>>(
        fh, fl, wth[3], wtl[3], nullptr, nullptr, nullptr, bf0, nullptr, nullptr, N);
    agg4_kernel<64, true, true, true, false><<<gridN4, TB, 0, stream>>>(
        bf0, csr, row_off, in_nrm, out_nrm, B4, bf1, nullptr, nullptr, N);

    // L5: 64->64 agg-first. th/tl = t5 = agg(g4) ; bf0 = g5
    agg4_kernel<64, false, false, false, true><<<gridN4, TB, 0, stream>>>(
        bf1, csr, row_off, nullptr, nullptr, nullptr, nullptr, th, tl, N);
    gemm_mfma<64, 64, true, true, true, false><<<MB, TB, 0, stream>>>(
        th, tl, wth[4], wtl[4], in_nrm, out_nrm, B5, bf0, nullptr, nullptr, N);

    // L6: 64->64 agg-first. th/tl = t6 = agg(g5) ; bf1 = g6
    agg4_kernel<64, false, false, false, true><<<gridN4, TB, 0, stream>>>(
        bf0, csr, row_off, nullptr, nullptr, nullptr, nullptr, th, tl, N);
    gemm_mfma<64, 64, true, true, true, false><<<MB, TB, 0, stream>>>(
        th, tl, wth[5], wtl[5], in_nrm, out_nrm, B6, bf1, nullptr, nullptr, N);

    // L7: 64->1 mult-first. bf0 = t7 = g6@W7 ; out = agg(t7)*r + B7
    gemv64_kernel<<<gridN4, TB, 0, stream>>>(bf1, W7, bf0, N);
    agg1_kernel<<<(N + 15) / 16, TB, 0, stream>>>(bf0, csr, row_off, in_nrm, B7, out, N);
}

// Round 4
// 343.766 us; speedup vs baseline: 1.3396x; 1.3396x over previous
//
#include <hip/hip_runtime.h>
#include <hip/hip_bf16.h>

// GCN 7-layer forward on MI355X. R4:
//  - hist rewrite: 600-block LDS histogram (R3's 160-block version was
//    latency-starved at 7% occupancy, 90-131us; deg atomics were 56us)
//  - fp16 aggregation payloads: gather bytes halve (~190us -> ~95us);
//    fp32 accumulate; GEMM A-operands stay split-bf16 (hi+lo planes)

#define IN_F 128
#define NSLICE 60
#define SHB 13          // 8192 nodes/shard, 32 KB LDS
#define NSHARD 5        // ceil(40960/8192)

typedef __attribute__((ext_vector_type(8))) short short8v;   // 8 bf16
typedef __attribute__((ext_vector_type(4))) float f32x4;
typedef __attribute__((ext_vector_type(8))) _Float16 half8v; // 16 B

static __device__ __forceinline__ unsigned short f2bf(float x) {
    unsigned u = __builtin_bit_cast(unsigned, x);
    unsigned r = (u + 0x7FFFu + ((u >> 16) & 1u)) >> 16;   // rn-even
    return (unsigned short)r;
}
static __device__ __forceinline__ float bf2f(unsigned short h) {
    unsigned u = ((unsigned)h) << 16;
    return __builtin_bit_cast(float, u);
}

// ---------------- LDS histogram: grid (NSLICE, NSHARD, 2) ----------------

__global__ __launch_bounds__(256) void hist2_kernel(const int* __restrict__ src,
                                                    const int* __restrict__ dst,
                                                    int* __restrict__ scratch, int E) {
    constexpr int SH = 1 << SHB;
    __shared__ int h[SH];
    const int t = threadIdx.x;
    const int b = blockIdx.x;            // edge slice
    const int s = blockIdx.y;            // node shard
    const int z = blockIdx.z;            // 0 = src (out-deg), 1 = dst (in-deg)
    const int* idx = z ? dst : src;
    for (int i = t; i < SH; i += 256) h[i] = 0;
    __syncthreads();
    const int per = (E + NSLICE - 1) / NSLICE;
    const int lo = b * per;
    const int hiE = min(lo + per, E);
    const int base = s << SHB;
    for (int e = lo + t; e < hiE; e += 256) {
        unsigned a = (unsigned)(idx[e] - base);
        if (a < (unsigned)SH) atomicAdd(&h[a], 1);
    }
    __syncthreads();
    int* so = scratch + ((size_t)((z * NSHARD + s) * NSLICE + b) << SHB);
    for (int i = t; i < SH; i += 256) so[i] = h[i];
}

__global__ void hist_reduce_kernel(const int* __restrict__ scratch,
                                   int* __restrict__ in_deg,
                                   float* __restrict__ out_nrm,
                                   float* __restrict__ in_nrm, int N) {
    constexpr int SH = 1 << SHB;
    int n = blockIdx.x * blockDim.x + threadIdx.x;
    if (n >= N) return;
    int s = n >> SHB;
    int i = n & (SH - 1);
    int od = 0, idg = 0;
    for (int b = 0; b < NSLICE; ++b) {
        od  += scratch[((size_t)((0 * NSHARD + s) * NSLICE + b) << SHB) + i];
        idg += scratch[((size_t)((1 * NSHARD + s) * NSLICE + b) << SHB) + i];
    }
    in_deg[n] = idg;
    out_nrm[n] = od  > 0 ? rsqrtf((float)od)  : 0.f;
    in_nrm[n]  = idg > 0 ? rsqrtf((float)idg) : 0.f;
}

// ---------------- multi-block exclusive scan of in_deg -> row_off ----------------

__global__ __launch_bounds__(256) void scan_blk_kernel(const int* __restrict__ deg,
                                                       int* __restrict__ blockSums, int N) {
    __shared__ int ws[4];
    const int t = threadIdx.x;
    const int base = blockIdx.x * 1024 + t * 4;
    int4 v = make_int4(0, 0, 0, 0);
    if (base + 3 < N) v = *reinterpret_cast<const int4*>(&deg[base]);
    else if (base < N) {
        v.x = deg[base];
        if (base + 1 < N) v.y = deg[base + 1];
        if (base + 2 < N) v.z = deg[base + 2];
    }
    int s = v.x + v.y + v.z + v.w;
#pragma unroll
    for (int off = 32; off > 0; off >>= 1) s += __shfl_down(s, off);
    if ((t & 63) == 0) ws[t >> 6] = s;
    __syncthreads();
    if (t == 0) blockSums[blockIdx.x] = ws[0] + ws[1] + ws[2] + ws[3];
}

__global__ __launch_bounds__(64) void scan_top_kernel(const int* __restrict__ blockSums,
                                                      int* __restrict__ blockOffs,
                                                      int* __restrict__ row_off, int NB, int N) {
    const int t = threadIdx.x;
    int orig = (t < NB) ? blockSums[t] : 0;
    int v = orig;
#pragma unroll
    for (int off = 1; off < 64; off <<= 1) {
        int u = __shfl_up(v, off);
        if (t >= off) v += u;
    }
    if (t < NB) blockOffs[t] = v - orig;
    if (t == 63) row_off[N] = v;
}

__global__ __launch_bounds__(256) void scan_fill_kernel(const int* __restrict__ deg,
                                                        const int* __restrict__ blockOffs,
                                                        int* __restrict__ row_off,
                                                        int* __restrict__ cursor, int N) {
    __shared__ int wtot[4];
    const int t = threadIdx.x;
    const int lane = t & 63;
    const int wid = t >> 6;
    const int base = blockIdx.x * 1024 + t * 4;
    int4 v = make_int4(0, 0, 0, 0);
    if (base + 3 < N) v = *reinterpret_cast<const int4*>(&deg[base]);
    else if (base < N) {
        v.x = deg[base];
        if (base + 1 < N) v.y = deg[base + 1];
        if (base + 2 < N) v.z = deg[base + 2];
    }
    const int s = v.x + v.y + v.z + v.w;
    int incl = s;
#pragma unroll
    for (int off = 1; off < 64; off <<= 1) {
        int u = __shfl_up(incl, off);
        if (lane >= off) incl += u;
    }
    if (lane == 63) wtot[wid] = incl;
    __syncthreads();
    int pre = blockOffs[blockIdx.x] + incl - s;
    for (int i = 0; i < wid; ++i) pre += wtot[i];
    if (base < N) {
        int run = pre;
        row_off[base] = run; cursor[base] = run; run += v.x;
        if (base + 1 < N) { row_off[base + 1] = run; cursor[base + 1] = run; run += v.y; }
        if (base + 2 < N) { row_off[base + 2] = run; cursor[base + 2] = run; run += v.z; }
        if (base + 3 < N) { row_off[base + 3] = run; cursor[base + 3] = run; }
    }
}

__global__ void fill_kernel(const int* __restrict__ src, const int* __restrict__ dst,
                            int* __restrict__ cursor, int* __restrict__ csr, int E) {
    int e = blockIdx.x * blockDim.x + threadIdx.x;
    if (e < E) {
        int pos = atomicAdd(&cursor[dst[e]], 1);
        csr[pos] = src[e];
    }
}

// ---------------- split conversions ----------------

__global__ void split_feat_kernel(const float* __restrict__ x, const float* __restrict__ snrm,
                                  unsigned short* __restrict__ th, unsigned short* __restrict__ tl,
                                  int total4) {
    int i = blockIdx.x * blockDim.x + threadIdx.x;
    if (i >= total4) return;
    float4 v = reinterpret_cast<const float4*>(x)[i];
    float sc = snrm[i >> 5];
    ushort4 h, l;
    float a;
    a = v.x * sc; h.x = f2bf(a); l.x = f2bf(a - bf2f(h.x));
    a = v.y * sc; h.y = f2bf(a); l.y = f2bf(a - bf2f(h.y));
    a = v.z * sc; h.z = f2bf(a); l.z = f2bf(a - bf2f(h.z));
    a = v.w * sc; h.w = f2bf(a); l.w = f2bf(a - bf2f(h.w));
    reinterpret_cast<ushort4*>(th)[i] = h;
    reinterpret_cast<ushort4*>(tl)[i] = l;
}

struct WDesc { const float* w; unsigned short* th; unsigned short* tl; int K; int N; };
struct WPack { WDesc d[6]; };

__global__ void split_w_kernel(WPack p) {
    WDesc d = p.d[blockIdx.x];
    int total = d.K * d.N;
    for (int i = threadIdx.x; i < total; i += blockDim.x) {
        int k = i / d.N, n = i - k * d.N;
        float v = d.w[i];
        unsigned short h = f2bf(v);
        d.th[(size_t)n * d.K + k] = h;
        d.tl[(size_t)n * d.K + k] = f2bf(v - bf2f(h));
    }
}

// ---------------- MFMA GEMM: Y = A @ Wt^T, split-bf16 operands ----------------
// OUTM: 0 = fp16 out, 1 = split-bf16 planes out

template<int K, int NOUT, bool POST, bool RELU, bool POST2, int OUTM>
__global__ __launch_bounds__(256) void gemm_mfma(
    const unsigned short* __restrict__ Ah, const unsigned short* __restrict__ Al,
    const unsigned short* __restrict__ Bh, const unsigned short* __restrict__ Bl,
    const float* __restrict__ r_nrm, const float* __restrict__ s_nrm,
    const float* __restrict__ bias,
    _Float16* __restrict__ Y16, unsigned short* __restrict__ Yh,
    unsigned short* __restrict__ Yl, int M) {
    constexpr int NT = NOUT / 16;
    const int lane = threadIdx.x & 63;
    const int wv = threadIdx.x >> 6;
    const int r0 = blockIdx.x * 64 + wv * 16;
    const int arow = r0 + (lane & 15);
    const int kg = (lane >> 4) * 8;

    f32x4 acc[NT];
#pragma unroll
    for (int n = 0; n < NT; ++n) acc[n] = (f32x4){0.f, 0.f, 0.f, 0.f};

    for (int kk = 0; kk < K; kk += 32) {
        short8v a_h = *reinterpret_cast<const short8v*>(Ah + (size_t)arow * K + kk + kg);
        short8v a_l = *reinterpret_cast<const short8v*>(Al + (size_t)arow * K + kk + kg);
#pragma unroll
        for (int n = 0; n < NT; ++n) {
            int col = n * 16 + (lane & 15);
            short8v b_h = *reinterpret_cast<const short8v*>(Bh + (size_t)col * K + kk + kg);
            short8v b_l = *reinterpret_cast<const short8v*>(Bl + (size_t)col * K + kk + kg);
            acc[n] = __builtin_amdgcn_mfma_f32_16x16x32_bf16(a_h, b_h, acc[n], 0, 0, 0);
            acc[n] = __builtin_amdgcn_mfma_f32_16x16x32_bf16(a_h, b_l, acc[n], 0, 0, 0);
            acc[n] = __builtin_amdgcn_mfma_f32_16x16x32_bf16(a_l, b_h, acc[n], 0, 0, 0);
        }
    }

    const int c0 = lane & 15;
    const int rr = r0 + (lane >> 4) * 4;
#pragma unroll
    for (int n = 0; n < NT; ++n) {
        const int col = n * 16 + c0;
        const float bcol = POST ? bias[col] : 0.f;
#pragma unroll
        for (int j = 0; j < 4; ++j) {
            const int row = rr + j;
            float y = acc[n][j];
            if (POST) y = fmaf(y, r_nrm[row], bcol);
            if (RELU) y = fmaxf(y, 0.f);
            if (POST2) y *= s_nrm[row];
            if (OUTM == 0) {
                Y16[(size_t)row * NOUT + col] = (_Float16)y;
            } else {
                unsigned short h = f2bf(y);
                Yh[(size_t)row * NOUT + col] = h;
                Yl[(size_t)row * NOUT + col] = f2bf(y - bf2f(h));
            }
        }
    }
}

// ---------------- fp16-payload CSR aggregation ----------------
// Each lane holds 8 features (16 B half8). F=64: 8 lanes/row, 8 edges/iter.
// F=128: 16 lanes/row, 4 edges/iter. fp32 accumulate.
// OUTM: 0 = fp16 out, 1 = split-bf16 planes out

template<int F, bool POST, bool RELU, bool POST2, int OUTM>
__global__ __launch_bounds__(256) void agg_h16(
    const _Float16* __restrict__ X, const int* __restrict__ csr,
    const int* __restrict__ row_off, const float* __restrict__ r_nrm,
    const float* __restrict__ s_nrm, const float* __restrict__ bias,
    _Float16* __restrict__ Y16, unsigned short* __restrict__ Yh,
    unsigned short* __restrict__ Yl, int N) {
    constexpr int LPE = F / 8;     // lanes per edge row
    constexpr int EPW = 64 / LPE;  // edges in flight
    const int lane = threadIdx.x & 63;
    const int node = blockIdx.x * (blockDim.x >> 6) + (threadIdx.x >> 6);
    if (node >= N) return;
    const int g = lane / LPE;
    const int c = lane % LPE;
    const int lo = row_off[node];
    const int hi = row_off[node + 1];
    float acc[8];
#pragma unroll
    for (int j = 0; j < 8; ++j) acc[j] = 0.f;
    for (int e = lo + g; e < hi; e += EPW) {
        int s = csr[e];
        half8v x = *reinterpret_cast<const half8v*>(&X[(size_t)s * F + c * 8]);
#pragma unroll
        for (int j = 0; j < 8; ++j) acc[j] += (float)x[j];
    }
#pragma unroll
    for (int m = LPE; m < 64; m <<= 1) {
#pragma unroll
        for (int j = 0; j < 8; ++j) acc[j] += __shfl_xor(acc[j], m);
    }
    if (lane < LPE) {
        if (POST) {
            float rn = r_nrm[node];
#pragma unroll
            for (int j = 0; j < 8; ++j) acc[j] = fmaf(acc[j], rn, bias[lane * 8 + j]);
        }
        if (RELU) {
#pragma unroll
            for (int j = 0; j < 8; ++j) acc[j] = fmaxf(acc[j], 0.f);
        }
        if (POST2) {
            float sn = s_nrm[node];
#pragma unroll
            for (int j = 0; j < 8; ++j) acc[j] *= sn;
        }
        if (OUTM == 0) {
            half8v o;
#pragma unroll
            for (int j = 0; j < 8; ++j) o[j] = (_Float16)acc[j];
            *reinterpret_cast<half8v*>(&Y16[(size_t)node * F + lane * 8]) = o;
        } else {
            short8v h, l;
#pragma unroll
            for (int j = 0; j < 8; ++j) {
                unsigned short hh = f2bf(acc[j]);
                h[j] = (short)hh;
                l[j] = (short)f2bf(acc[j] - bf2f(hh));
            }
            *reinterpret_cast<short8v*>(&Yh[(size_t)node * F + lane * 8]) = h;
            *reinterpret_cast<short8v*>(&Yl[(size_t)node * F + lane * 8]) = l;
        }
    }
}

// ---------------- layer 7 ----------------

__global__ __launch_bounds__(256) void gemv64_kernel(const _Float16* __restrict__ X,
                                                     const float* __restrict__ W,
                                                     float* __restrict__ Y, int M) {
    const int lane = threadIdx.x & 63;
    const int m = blockIdx.x * (blockDim.x >> 6) + (threadIdx.x >> 6);
    if (m >= M) return;
    float v = (float)X[(size_t)m * 64 + lane] * W[lane];
#pragma unroll
    for (int off = 32; off > 0; off >>= 1) v += __shfl_down(v, off);
    if (lane == 0) Y[m] = v;
}

__global__ __launch_bounds__(256) void agg1_kernel(const float* __restrict__ T,
                                                   const int* __restrict__ csr,
                                                   const int* __restrict__ row_off,
                                                   const float* __restrict__ r_nrm,
                                                   const float* __restrict__ bias,
                                                   float* __restrict__ Y, int N) {
    const int node = blockIdx.x * 16 + (threadIdx.x >> 4);
    const int l = threadIdx.x & 15;
    if (node >= N) return;
    const int lo = row_off[node];
    const int hi = row_off[node + 1];
    float acc = 0.f;
    for (int e = lo + l; e < hi; e += 16) acc += T[csr[e]];
#pragma unroll
    for (int m = 8; m >= 1; m >>= 1) acc += __shfl_xor(acc, m);
    if (l == 0) Y[node] = fmaf(acc, r_nrm[node], bias[0]);
}

// ---------------- host ----------------

extern "C" void kernel_launch(void* const* d_in, const int* in_sizes, int n_in,
                              void* d_out, int out_size, void* d_ws, size_t ws_size,
                              hipStream_t stream) {
    const float* in_feat = (const float*)d_in[0];
    const int* src = (const int*)d_in[1];
    const int* dst = (const int*)d_in[2];
    const float* W1 = (const float*)d_in[3];  const float* B1 = (const float*)d_in[4];
    const float* W2 = (const float*)d_in[5];  const float* B2 = (const float*)d_in[6];
    const float* W3 = (const float*)d_in[7];  const float* B3 = (const float*)d_in[8];
    const float* W4 = (const float*)d_in[9];  const float* B4 = (const float*)d_in[10];
    const float* W5 = (const float*)d_in[11]; const float* B5 = (const float*)d_in[12];
    const float* W6 = (const float*)d_in[13]; const float* B6 = (const float*)d_in[14];
    const float* W7 = (const float*)d_in[15]; const float* B7 = (const float*)d_in[16];

    const int N = in_sizes[0] / IN_F;   // 40000
    const int E = in_sizes[1];          // 640000
    float* out = (float*)d_out;

    // workspace layout (256B aligned)
    char* w = (char*)d_ws;
    auto alloc = [&](size_t bytes) { char* p = w; w += (bytes + 255) & ~(size_t)255; return p; };
    int* csr      = (int*)alloc((size_t)E * 4);
    int* row_off  = (int*)alloc((size_t)(N + 1) * 4);
    int* cursor   = (int*)alloc((size_t)N * 4);
    int* in_deg   = (int*)alloc((size_t)N * 4);
    int* blockSums= (int*)alloc(64 * 4);
    int* blockOffs= (int*)alloc(64 * 4);
    float* out_nrm= (float*)alloc((size_t)N * 4);
    float* in_nrm = (float*)alloc((size_t)N * 4);
    float* t7     = (float*)alloc((size_t)N * 4);
    const int dims[8] = {128, 64, 128, 128, 64, 64, 64, 1};
    unsigned short* wth[6]; unsigned short* wtl[6];
    for (int i = 0; i < 6; ++i) {
        size_t kn = (size_t)dims[i] * dims[i + 1];
        wth[i] = (unsigned short*)alloc(kn * 2);
        wtl[i] = (unsigned short*)alloc(kn * 2);
    }
    unsigned short* fh = (unsigned short*)alloc((size_t)N * 128 * 2);
    unsigned short* fl = (unsigned short*)alloc((size_t)N * 128 * 2);
    unsigned short* th = (unsigned short*)alloc((size_t)N * 128 * 2);
    unsigned short* tl = (unsigned short*)alloc((size_t)N * 128 * 2);
    _Float16* h0 = (_Float16*)alloc((size_t)N * 128 * 2);
    _Float16* h1 = (_Float16*)alloc((size_t)N * 128 * 2);
    // hist scratch aliases fh+fl (2*NSHARD*NSLICE*8192*4 = 19.7MB <= 20.5MB);
    // consumed by hist_reduce before split_feat writes fh/fl.
    int* scratch = (int*)fh;
    (void)ws_size; (void)n_in; (void)out_size;

    const int TB = 256;
    const int NB = (N + 1023) / 1024;   // 40

    // weight split/transpose (independent)
    WPack wp;
    const float* Ws[6] = {W1, W2, W3, W4, W5, W6};
    for (int i = 0; i < 6; ++i) wp.d[i] = {Ws[i], wth[i], wtl[i], dims[i], dims[i + 1]};
    split_w_kernel<<<6, TB, 0, stream>>>(wp);

    // degrees + norms + CSR
    hist2_kernel<<<dim3(NSLICE, NSHARD, 2), TB, 0, stream>>>(src, dst, scratch, E);
    hist_reduce_kernel<<<(N + TB - 1) / TB, TB, 0, stream>>>(
        scratch, in_deg, out_nrm, in_nrm, N);
    scan_blk_kernel<<<NB, TB, 0, stream>>>(in_deg, blockSums, N);
    scan_top_kernel<<<1, 64, 0, stream>>>(blockSums, blockOffs, row_off, NB, N);
    scan_fill_kernel<<<NB, TB, 0, stream>>>(in_deg, blockOffs, row_off, cursor, N);
    fill_kernel<<<(E + TB - 1) / TB, TB, 0, stream>>>(src, dst, cursor, csr, E);

    // input split (after hist_reduce freed scratch)
    split_feat_kernel<<<(N * 32 + TB - 1) / TB, TB, 0, stream>>>(
        in_feat, out_nrm, fh, fl, N * 32);

    const int gridN4 = (N + 3) / 4;
    const int MB = N / 64;   // 625

    // L1: 128->64 mult-first. h0 = t1 = split(x*s)@W1 ; h1 = g1 = relu(agg(t1)*r+B1)*s
    gemm_mfma<128, 64, false, false, false, 0><<<MB, TB, 0, stream>>>(
        fh, fl, wth[0], wtl[0], nullptr, nullptr, nullptr, h0, nullptr, nullptr, N);
    agg_h16<64, true, true, true, 0><<<gridN4, TB, 0, stream>>>(
        h0, csr, row_off, in_nrm, out_nrm, B1, h1, nullptr, nullptr, N);

    // L2: 64->128 agg-first. th/tl = t2 = agg(g1) ; h0 = g2 = relu(t2@W2*r+B2)*s
    agg_h16<64, false, false, false, 1><<<gridN4, TB, 0, stream>>>(
        h1, csr, row_off, nullptr, nullptr, nullptr, nullptr, th, tl, N);
    gemm_mfma<64, 128, true, true, true, 0><<<MB, TB, 0, stream>>>(
        th, tl, wth[1], wtl[1], in_nrm, out_nrm, B2, h0, nullptr, nullptr, N);

    // L3: 128->128 agg-first. th/tl = t3 = agg(g2) ; fh/fl = g3 (split, feeds L4 gemm)
    agg_h16<128, false, false, false, 1><<<gridN4, TB, 0, stream>>>(
        h0, csr, row_off, nullptr, nullptr, nullptr, nullptr, th, tl, N);
    gemm_mfma<128, 128, true, true, true, 1><<<MB, TB, 0, stream>>>(
        th, tl, wth[2], wtl[2], in_nrm, out_nrm, B3, nullptr, fh, fl, N);

    // L4: 128->64 mult-first. h0 = t4 = g3@W4 ; h1 = g4 = relu(agg(t4)*r+B4)*s
    gemm_mfma<128, 64, false, false, false, 0><<<MB, TB, 0, stream>>>(
        fh, fl, wth[3], wtl[3], nullptr, nullptr, nullptr, h0, nullptr, nullptr, N);
    agg_h16<64, true, true, true, 0><<<gridN4, TB, 0, stream>>>(
        h0, csr, row_off, in_nrm, out_nrm, B4, h1, nullptr, nullptr, N);

    // L5: 64->64 agg-first. th/tl = t5 = agg(g4) ; h0 = g5
    agg_h16<64, false, false, false, 1><<<gridN4, TB, 0, stream>>>(
        h1, csr, row_off, nullptr, nullptr, nullptr, nullptr, th, tl, N);
    gemm_mfma<64, 64, true, true, true, 0><<<MB, TB, 0, stream>>>(
        th, tl, wth[4], wtl[4], in_nrm, out_nrm, B5, h0, nullptr, nullptr, N);

    // L6: 64->64 agg-first. th/tl = t6 = agg(g5) ; h1 = g6
    agg_h16<64, false, false, false, 1><<<gridN4, TB, 0, stream>>>(
        h0, csr, row_off, nullptr, nullptr, nullptr, nullptr, th, tl, N);
    gemm_mfma<64, 64, true, true, true, 0><<<MB, TB, 0, stream>>>(
        th, tl, wth[5], wtl[5], in_nrm, out_nrm, B6, h1, nullptr, nullptr, N);

    // L7: 64->1 mult-first. t7 = g6@W7 ; out = agg(t7)*r + B7
    gemv64_kernel<<<gridN4, TB, 0, stream>>>(h1, W7, t7, N);
    agg1_kernel<<<(N + 15) / 16, TB, 0, stream>>>(t7, csr, row_off, in_nrm, B7, out, N);
}

// Round 5
// 310.160 us; speedup vs baseline: 1.4848x; 1.1083x over previous
//
#include <hip/hip_runtime.h>
#include <hip/hip_bf16.h>

// GCN 7-layer forward on MI355X. R5:
//  - split_w parallelized (was 6 blocks / 49us -> grid(6,64), ~1us)
//  - atomic-free CSR fill: per-slice dst-histograms -> per-(slice,node) base
//    positions (slice_base) -> LDS-cursor placement (fill2). no global atomics.
//  - agg edge loop 2x unrolled (dual accumulators, 16 loads in flight)

#define IN_F 128
#define NSLICE 60
#define SHB 13          // 8192 nodes/shard, 32 KB LDS
#define NSHARD 5        // ceil(40000/8192)

typedef __attribute__((ext_vector_type(8))) short short8v;   // 8 bf16
typedef __attribute__((ext_vector_type(4))) float f32x4;
typedef __attribute__((ext_vector_type(8))) _Float16 half8v; // 16 B

static __device__ __forceinline__ unsigned short f2bf(float x) {
    unsigned u = __builtin_bit_cast(unsigned, x);
    unsigned r = (u + 0x7FFFu + ((u >> 16) & 1u)) >> 16;   // rn-even
    return (unsigned short)r;
}
static __device__ __forceinline__ float bf2f(unsigned short h) {
    unsigned u = ((unsigned)h) << 16;
    return __builtin_bit_cast(float, u);
}

// ---------------- LDS histogram: grid (NSLICE, NSHARD, 2) ----------------

__global__ __launch_bounds__(256) void hist2_kernel(const int* __restrict__ src,
                                                    const int* __restrict__ dst,
                                                    int* __restrict__ scratch, int E) {
    constexpr int SH = 1 << SHB;
    __shared__ int h[SH];
    const int t = threadIdx.x;
    const int b = blockIdx.x;            // edge slice
    const int s = blockIdx.y;            // node shard
    const int z = blockIdx.z;            // 0 = src (out-deg), 1 = dst (in-deg)
    const int* idx = z ? dst : src;
    for (int i = t; i < SH; i += 256) h[i] = 0;
    __syncthreads();
    const int per = (E + NSLICE - 1) / NSLICE;
    const int lo = b * per;
    const int hiE = min(lo + per, E);
    const int base = s << SHB;
    for (int e = lo + t; e < hiE; e += 256) {
        unsigned a = (unsigned)(idx[e] - base);
        if (a < (unsigned)SH) atomicAdd(&h[a], 1);
    }
    __syncthreads();
    int* so = scratch + ((size_t)((z * NSHARD + s) * NSLICE + b) << SHB);
    for (int i = t; i < SH; i += 256) so[i] = h[i];
}

__global__ void hist_reduce_kernel(const int* __restrict__ scratch,
                                   int* __restrict__ in_deg,
                                   float* __restrict__ out_nrm,
                                   float* __restrict__ in_nrm, int N) {
    constexpr int SH = 1 << SHB;
    int n = blockIdx.x * blockDim.x + threadIdx.x;
    if (n >= N) return;
    int s = n >> SHB;
    int i = n & (SH - 1);
    int od = 0, idg = 0;
    for (int b = 0; b < NSLICE; ++b) {
        od  += scratch[((size_t)((0 * NSHARD + s) * NSLICE + b) << SHB) + i];
        idg += scratch[((size_t)((1 * NSHARD + s) * NSLICE + b) << SHB) + i];
    }
    in_deg[n] = idg;
    out_nrm[n] = od  > 0 ? rsqrtf((float)od)  : 0.f;
    in_nrm[n]  = idg > 0 ? rsqrtf((float)idg) : 0.f;
}

// ---------------- multi-block exclusive scan of in_deg -> row_off ----------------

__global__ __launch_bounds__(256) void scan_blk_kernel(const int* __restrict__ deg,
                                                       int* __restrict__ blockSums, int N) {
    __shared__ int ws[4];
    const int t = threadIdx.x;
    const int base = blockIdx.x * 1024 + t * 4;
    int4 v = make_int4(0, 0, 0, 0);
    if (base + 3 < N) v = *reinterpret_cast<const int4*>(&deg[base]);
    else if (base < N) {
        v.x = deg[base];
        if (base + 1 < N) v.y = deg[base + 1];
        if (base + 2 < N) v.z = deg[base + 2];
    }
    int s = v.x + v.y + v.z + v.w;
#pragma unroll
    for (int off = 32; off > 0; off >>= 1) s += __shfl_down(s, off);
    if ((t & 63) == 0) ws[t >> 6] = s;
    __syncthreads();
    if (t == 0) blockSums[blockIdx.x] = ws[0] + ws[1] + ws[2] + ws[3];
}

__global__ __launch_bounds__(64) void scan_top_kernel(const int* __restrict__ blockSums,
                                                      int* __restrict__ blockOffs,
                                                      int* __restrict__ row_off, int NB, int N) {
    const int t = threadIdx.x;
    int orig = (t < NB) ? blockSums[t] : 0;
    int v = orig;
#pragma unroll
    for (int off = 1; off < 64; off <<= 1) {
        int u = __shfl_up(v, off);
        if (t >= off) v += u;
    }
    if (t < NB) blockOffs[t] = v - orig;
    if (t == 63) row_off[N] = v;
}

__global__ __launch_bounds__(256) void scan_fill_kernel(const int* __restrict__ deg,
                                                        const int* __restrict__ blockOffs,
                                                        int* __restrict__ row_off, int N) {
    __shared__ int wtot[4];
    const int t = threadIdx.x;
    const int lane = t & 63;
    const int wid = t >> 6;
    const int base = blockIdx.x * 1024 + t * 4;
    int4 v = make_int4(0, 0, 0, 0);
    if (base + 3 < N) v = *reinterpret_cast<const int4*>(&deg[base]);
    else if (base < N) {
        v.x = deg[base];
        if (base + 1 < N) v.y = deg[base + 1];
        if (base + 2 < N) v.z = deg[base + 2];
    }
    const int s = v.x + v.y + v.z + v.w;
    int incl = s;
#pragma unroll
    for (int off = 1; off < 64; off <<= 1) {
        int u = __shfl_up(incl, off);
        if (lane >= off) incl += u;
    }
    if (lane == 63) wtot[wid] = incl;
    __syncthreads();
    int pre = blockOffs[blockIdx.x] + incl - s;
    for (int i = 0; i < wid; ++i) pre += wtot[i];
    if (base < N) {
        int run = pre;
        row_off[base] = run; run += v.x;
        if (base + 1 < N) { row_off[base + 1] = run; run += v.y; }
        if (base + 2 < N) { row_off[base + 2] = run; run += v.z; }
        if (base + 3 < N) { row_off[base + 3] = run; }
    }
}

// convert per-(slice,node) dst counts (z=1 region) into global base positions:
// scratch[b][n] <- row_off[n] + sum_{b'<b} cnt[b'][n]
__global__ void slice_base_kernel(int* __restrict__ scratch,
                                  const int* __restrict__ row_off, int N) {
    constexpr int SH = 1 << SHB;
    int n = blockIdx.x * blockDim.x + threadIdx.x;
    if (n >= N) return;
    int s = n >> SHB;
    int i = n & (SH - 1);
    int run = row_off[n];
    for (int b = 0; b < NSLICE; ++b) {
        size_t off = ((size_t)((NSHARD + s) * NSLICE + b) << SHB) + i;
        int c = scratch[off];
        scratch[off] = run;
        run += c;
    }
}

// place edges using LDS cursors seeded from slice bases; no global atomics
__global__ __launch_bounds__(256) void fill2_kernel(const int* __restrict__ src,
                                                    const int* __restrict__ dst,
                                                    const int* __restrict__ scratch,
                                                    int* __restrict__ csr, int E) {
    constexpr int SH = 1 << SHB;
    __shared__ int cur[SH];
    const int t = threadIdx.x;
    const int b = blockIdx.x;   // slice
    const int s = blockIdx.y;   // shard
    const int* base = scratch + ((size_t)((NSHARD + s) * NSLICE + b) << SHB);
    for (int i = t; i < SH; i += 256) cur[i] = base[i];
    __syncthreads();
    const int per = (E + NSLICE - 1) / NSLICE;
    const int lo = b * per;
    const int hiE = min(lo + per, E);
    const int nb = s << SHB;
    for (int e = lo + t; e < hiE; e += 256) {
        unsigned a = (unsigned)(dst[e] - nb);
        if (a < (unsigned)SH) {
            int pos = atomicAdd(&cur[a], 1);
            csr[pos] = src[e];
        }
    }
}

// ---------------- split conversions ----------------

__global__ void split_feat_kernel(const float* __restrict__ x, const float* __restrict__ snrm,
                                  unsigned short* __restrict__ th, unsigned short* __restrict__ tl,
                                  int total4) {
    int i = blockIdx.x * blockDim.x + threadIdx.x;
    if (i >= total4) return;
    float4 v = reinterpret_cast<const float4*>(x)[i];
    float sc = snrm[i >> 5];
    ushort4 h, l;
    float a;
    a = v.x * sc; h.x = f2bf(a); l.x = f2bf(a - bf2f(h.x));
    a = v.y * sc; h.y = f2bf(a); l.y = f2bf(a - bf2f(h.y));
    a = v.z * sc; h.z = f2bf(a); l.z = f2bf(a - bf2f(h.z));
    a = v.w * sc; h.w = f2bf(a); l.w = f2bf(a - bf2f(h.w));
    reinterpret_cast<ushort4*>(th)[i] = h;
    reinterpret_cast<ushort4*>(tl)[i] = l;
}

struct WDesc { const float* w; unsigned short* th; unsigned short* tl; int K; int N; };
struct WPack { WDesc d[6]; };

// one element per thread; grid (6 weights, 64 chunks)
__global__ __launch_bounds__(256) void split_w_kernel(WPack p) {
    WDesc d = p.d[blockIdx.x];
    int i = blockIdx.y * 256 + threadIdx.x;
    if (i >= d.K * d.N) return;
    int k = i / d.N, n = i - k * d.N;
    float v = d.w[i];
    unsigned short h = f2bf(v);
    d.th[(size_t)n * d.K + k] = h;
    d.tl[(size_t)n * d.K + k] = f2bf(v - bf2f(h));
}

// ---------------- MFMA GEMM: Y = A @ Wt^T, split-bf16 operands ----------------
// OUTM: 0 = fp16 out, 1 = split-bf16 planes out

template<int K, int NOUT, bool POST, bool RELU, bool POST2, int OUTM>
__global__ __launch_bounds__(256) void gemm_mfma(
    const unsigned short* __restrict__ Ah, const unsigned short* __restrict__ Al,
    const unsigned short* __restrict__ Bh, const unsigned short* __restrict__ Bl,
    const float* __restrict__ r_nrm, const float* __restrict__ s_nrm,
    const float* __restrict__ bias,
    _Float16* __restrict__ Y16, unsigned short* __restrict__ Yh,
    unsigned short* __restrict__ Yl, int M) {
    constexpr int NT = NOUT / 16;
    const int lane = threadIdx.x & 63;
    const int wv = threadIdx.x >> 6;
    const int r0 = blockIdx.x * 64 + wv * 16;
    const int arow = r0 + (lane & 15);
    const int kg = (lane >> 4) * 8;

    f32x4 acc[NT];
#pragma unroll
    for (int n = 0; n < NT; ++n) acc[n] = (f32x4){0.f, 0.f, 0.f, 0.f};

    for (int kk = 0; kk < K; kk += 32) {
        short8v a_h = *reinterpret_cast<const short8v*>(Ah + (size_t)arow * K + kk + kg);
        short8v a_l = *reinterpret_cast<const short8v*>(Al + (size_t)arow * K + kk + kg);
#pragma unroll
        for (int n = 0; n < NT; ++n) {
            int col = n * 16 + (lane & 15);
            short8v b_h = *reinterpret_cast<const short8v*>(Bh + (size_t)col * K + kk + kg);
            short8v b_l = *reinterpret_cast<const short8v*>(Bl + (size_t)col * K + kk + kg);
            acc[n] = __builtin_amdgcn_mfma_f32_16x16x32_bf16(a_h, b_h, acc[n], 0, 0, 0);
            acc[n] = __builtin_amdgcn_mfma_f32_16x16x32_bf16(a_h, b_l, acc[n], 0, 0, 0);
            acc[n] = __builtin_amdgcn_mfma_f32_16x16x32_bf16(a_l, b_h, acc[n], 0, 0, 0);
        }
    }

    const int c0 = lane & 15;
    const int rr = r0 + (lane >> 4) * 4;
#pragma unroll
    for (int n = 0; n < NT; ++n) {
        const int col = n * 16 + c0;
        const float bcol = POST ? bias[col] : 0.f;
#pragma unroll
        for (int j = 0; j < 4; ++j) {
            const int row = rr + j;
            float y = acc[n][j];
            if (POST) y = fmaf(y, r_nrm[row], bcol);
            if (RELU) y = fmaxf(y, 0.f);
            if (POST2) y *= s_nrm[row];
            if (OUTM == 0) {
                Y16[(size_t)row * NOUT + col] = (_Float16)y;
            } else {
                unsigned short h = f2bf(y);
                Yh[(size_t)row * NOUT + col] = h;
                Yl[(size_t)row * NOUT + col] = f2bf(y - bf2f(h));
            }
        }
    }
}

// ---------------- fp16-payload CSR aggregation, 2x unrolled ----------------
// F=64: 8 lanes/row, 8 edges/iter (16 with unroll). F=128: 16 lanes/row, 4 (8).

template<int F, bool POST, bool RELU, bool POST2, int OUTM>
__global__ __launch_bounds__(256) void agg_h16(
    const _Float16* __restrict__ X, const int* __restrict__ csr,
    const int* __restrict__ row_off, const float* __restrict__ r_nrm,
    const float* __restrict__ s_nrm, const float* __restrict__ bias,
    _Float16* __restrict__ Y16, unsigned short* __restrict__ Yh,
    unsigned short* __restrict__ Yl, int N) {
    constexpr int LPE = F / 8;     // lanes per edge row
    constexpr int EPW = 64 / LPE;  // edges in flight (per unroll step)
    const int lane = threadIdx.x & 63;
    const int node = blockIdx.x * (blockDim.x >> 6) + (threadIdx.x >> 6);
    if (node >= N) return;
    const int g = lane / LPE;
    const int c = lane % LPE;
    const int lo = row_off[node];
    const int hi = row_off[node + 1];
    float acc[8], acc2[8];
#pragma unroll
    for (int j = 0; j < 8; ++j) { acc[j] = 0.f; acc2[j] = 0.f; }
    int e = lo + g;
    for (; e + EPW < hi; e += 2 * EPW) {
        int s0 = csr[e];
        int s1 = csr[e + EPW];
        half8v x0 = *reinterpret_cast<const half8v*>(&X[(size_t)s0 * F + c * 8]);
        half8v x1 = *reinterpret_cast<const half8v*>(&X[(size_t)s1 * F + c * 8]);
#pragma unroll
        for (int j = 0; j < 8; ++j) { acc[j] += (float)x0[j]; acc2[j] += (float)x1[j]; }
    }
    if (e < hi) {
        int s0 = csr[e];
        half8v x0 = *reinterpret_cast<const half8v*>(&X[(size_t)s0 * F + c * 8]);
#pragma unroll
        for (int j = 0; j < 8; ++j) acc[j] += (float)x0[j];
    }
#pragma unroll
    for (int j = 0; j < 8; ++j) acc[j] += acc2[j];
#pragma unroll
    for (int m = LPE; m < 64; m <<= 1) {
#pragma unroll
        for (int j = 0; j < 8; ++j) acc[j] += __shfl_xor(acc[j], m);
    }
    if (lane < LPE) {
        if (POST) {
            float rn = r_nrm[node];
#pragma unroll
            for (int j = 0; j < 8; ++j) acc[j] = fmaf(acc[j], rn, bias[lane * 8 + j]);
        }
        if (RELU) {
#pragma unroll
            for (int j = 0; j < 8; ++j) acc[j] = fmaxf(acc[j], 0.f);
        }
        if (POST2) {
            float sn = s_nrm[node];
#pragma unroll
            for (int j = 0; j < 8; ++j) acc[j] *= sn;
        }
        if (OUTM == 0) {
            half8v o;
#pragma unroll
            for (int j = 0; j < 8; ++j) o[j] = (_Float16)acc[j];
            *reinterpret_cast<half8v*>(&Y16[(size_t)node * F + lane * 8]) = o;
        } else {
            short8v h, l;
#pragma unroll
            for (int j = 0; j < 8; ++j) {
                unsigned short hh = f2bf(acc[j]);
                h[j] = (short)hh;
                l[j] = (short)f2bf(acc[j] - bf2f(hh));
            }
            *reinterpret_cast<short8v*>(&Yh[(size_t)node * F + lane * 8]) = h;
            *reinterpret_cast<short8v*>(&Yl[(size_t)node * F + lane * 8]) = l;
        }
    }
}

// ---------------- layer 7 ----------------

__global__ __launch_bounds__(256) void gemv64_kernel(const _Float16* __restrict__ X,
                                                     const float* __restrict__ W,
                                                     float* __restrict__ Y, int M) {
    const int lane = threadIdx.x & 63;
    const int m = blockIdx.x * (blockDim.x >> 6) + (threadIdx.x >> 6);
    if (m >= M) return;
    float v = (float)X[(size_t)m * 64 + lane] * W[lane];
#pragma unroll
    for (int off = 32; off > 0; off >>= 1) v += __shfl_down(v, off);
    if (lane == 0) Y[m] = v;
}

__global__ __launch_bounds__(256) void agg1_kernel(const float* __restrict__ T,
                                                   const int* __restrict__ csr,
                                                   const int* __restrict__ row_off,
                                                   const float* __restrict__ r_nrm,
                                                   const float* __restrict__ bias,
                                                   float* __restrict__ Y, int N) {
    const int node = blockIdx.x * 16 + (threadIdx.x >> 4);
    const int l = threadIdx.x & 15;
    if (node >= N) return;
    const int lo = row_off[node];
    const int hi = row_off[node + 1];
    float acc = 0.f;
    for (int e = lo + l; e < hi; e += 16) acc += T[csr[e]];
#pragma unroll
    for (int m = 8; m >= 1; m >>= 1) acc += __shfl_xor(acc, m);
    if (l == 0) Y[node] = fmaf(acc, r_nrm[node], bias[0]);
}

// ---------------- host ----------------

extern "C" void kernel_launch(void* const* d_in, const int* in_sizes, int n_in,
                              void* d_out, int out_size, void* d_ws, size_t ws_size,
                              hipStream_t stream) {
    const float* in_feat = (const float*)d_in[0];
    const int* src = (const int*)d_in[1];
    const int* dst = (const int*)d_in[2];
    const float* W1 = (const float*)d_in[3];  const float* B1 = (const float*)d_in[4];
    const float* W2 = (const float*)d_in[5];  const float* B2 = (const float*)d_in[6];
    const float* W3 = (const float*)d_in[7];  const float* B3 = (const float*)d_in[8];
    const float* W4 = (const float*)d_in[9];  const float* B4 = (const float*)d_in[10];
    const float* W5 = (const float*)d_in[11]; const float* B5 = (const float*)d_in[12];
    const float* W6 = (const float*)d_in[13]; const float* B6 = (const float*)d_in[14];
    const float* W7 = (const float*)d_in[15]; const float* B7 = (const float*)d_in[16];

    const int N = in_sizes[0] / IN_F;   // 40000
    const int E = in_sizes[1];          // 640000
    float* out = (float*)d_out;

    // workspace layout (256B aligned)
    char* w = (char*)d_ws;
    auto alloc = [&](size_t bytes) { char* p = w; w += (bytes + 255) & ~(size_t)255; return p; };
    int* csr      = (int*)alloc((size_t)E * 4);
    int* row_off  = (int*)alloc((size_t)(N + 1) * 4);
    int* in_deg   = (int*)alloc((size_t)N * 4);
    int* blockSums= (int*)alloc(64 * 4);
    int* blockOffs= (int*)alloc(64 * 4);
    float* out_nrm= (float*)alloc((size_t)N * 4);
    float* in_nrm = (float*)alloc((size_t)N * 4);
    float* t7     = (float*)alloc((size_t)N * 4);
    const int dims[8] = {128, 64, 128, 128, 64, 64, 64, 1};
    unsigned short* wth[6]; unsigned short* wtl[6];
    for (int i = 0; i < 6; ++i) {
        size_t kn = (size_t)dims[i] * dims[i + 1];
        wth[i] = (unsigned short*)alloc(kn * 2);
        wtl[i] = (unsigned short*)alloc(kn * 2);
    }
    unsigned short* fh = (unsigned short*)alloc((size_t)N * 128 * 2);
    unsigned short* fl = (unsigned short*)alloc((size_t)N * 128 * 2);
    unsigned short* th = (unsigned short*)alloc((size_t)N * 128 * 2);
    unsigned short* tl = (unsigned short*)alloc((size_t)N * 128 * 2);
    _Float16* h0 = (_Float16*)alloc((size_t)N * 128 * 2);
    _Float16* h1 = (_Float16*)alloc((size_t)N * 128 * 2);
    // hist scratch aliases fh+fl (2*NSHARD*NSLICE*8192*4 = 19.66MB <= 20.48MB);
    // consumed by fill2 before split_feat writes fh/fl.
    int* scratch = (int*)fh;
    (void)ws_size; (void)n_in; (void)out_size;

    const int TB = 256;
    const int NB = (N + 1023) / 1024;   // 40

    // weight split/transpose (independent; one element/thread)
    WPack wp;
    const float* Ws[6] = {W1, W2, W3, W4, W5, W6};
    for (int i = 0; i < 6; ++i) wp.d[i] = {Ws[i], wth[i], wtl[i], dims[i], dims[i + 1]};
    split_w_kernel<<<dim3(6, 64), TB, 0, stream>>>(wp);

    // degrees + norms + CSR (atomic-free)
    hist2_kernel<<<dim3(NSLICE, NSHARD, 2), TB, 0, stream>>>(src, dst, scratch, E);
    hist_reduce_kernel<<<(N + TB - 1) / TB, TB, 0, stream>>>(
        scratch, in_deg, out_nrm, in_nrm, N);
    scan_blk_kernel<<<NB, TB, 0, stream>>>(in_deg, blockSums, N);
    scan_top_kernel<<<1, 64, 0, stream>>>(blockSums, blockOffs, row_off, NB, N);
    scan_fill_kernel<<<NB, TB, 0, stream>>>(in_deg, blockOffs, row_off, N);
    slice_base_kernel<<<(N + TB - 1) / TB, TB, 0, stream>>>(scratch, row_off, N);
    fill2_kernel<<<dim3(NSLICE, NSHARD), TB, 0, stream>>>(src, dst, scratch, csr, E);

    // input split (after fill2 freed scratch)
    split_feat_kernel<<<(N * 32 + TB - 1) / TB, TB, 0, stream>>>(
        in_feat, out_nrm, fh, fl, N * 32);

    const int gridN4 = (N + 3) / 4;
    const int MB = N / 64;   // 625

    // L1: 128->64 mult-first. h0 = t1 = split(x*s)@W1 ; h1 = g1 = relu(agg(t1)*r+B1)*s
    gemm_mfma<128, 64, false, false, false, 0><<<MB, TB, 0, stream>>>(
        fh, fl, wth[0], wtl[0], nullptr, nullptr, nullptr, h0, nullptr, nullptr, N);
    agg_h16<64, true, true, true, 0><<<gridN4, TB, 0, stream>>>(
        h0, csr, row_off, in_nrm, out_nrm, B1, h1, nullptr, nullptr, N);

    // L2: 64->128 agg-first. th/tl = t2 = agg(g1) ; h0 = g2 = relu(t2@W2*r+B2)*s
    agg_h16<64, false, false, false, 1><<<gridN4, TB, 0, stream>>>(
        h1, csr, row_off, nullptr, nullptr, nullptr, nullptr, th, tl, N);
    gemm_mfma<64, 128, true, true, true, 0><<<MB, TB, 0, stream>>>(
        th, tl, wth[1], wtl[1], in_nrm, out_nrm, B2, h0, nullptr, nullptr, N);

    // L3: 128->128 agg-first. th/tl = t3 = agg(g2) ; fh/fl = g3 (split, feeds L4 gemm)
    agg_h16<128, false, false, false, 1><<<gridN4, TB, 0, stream>>>(
        h0, csr, row_off, nullptr, nullptr, nullptr, nullptr, th, tl, N);
    gemm_mfma<128, 128, true, true, true, 1><<<MB, TB, 0, stream>>>(
        th, tl, wth[2], wtl[2], in_nrm, out_nrm, B3, nullptr, fh, fl, N);

    // L4: 128->64 mult-first. h0 = t4 = g3@W4 ; h1 = g4 = relu(agg(t4)*r+B4)*s
    gemm_mfma<128, 64, false, false, false, 0><<<MB, TB, 0, stream>>>(
        fh, fl, wth[3], wtl[3], nullptr, nullptr, nullptr, h0, nullptr, nullptr, N);
    agg_h16<64, true, true, true, 0><<<gridN4, TB, 0, stream>>>(
        h0, csr, row_off, in_nrm, out_nrm, B4, h1, nullptr, nullptr, N);

    // L5: 64->64 agg-first. th/tl = t5 = agg(g4) ; h0 = g5
    agg_h16<64, false, false, false, 1><<<gridN4, TB, 0, stream>>>(
        h1, csr, row_off, nullptr, nullptr, nullptr, nullptr, th, tl, N);
    gemm_mfma<64, 64, true, true, true, 0><<<MB, TB, 0, stream>>>(
        th, tl, wth[4], wtl[4], in_nrm, out_nrm, B5, h0, nullptr, nullptr, N);

    // L6: 64->64 agg-first. th/tl = t6 = agg(g5) ; h1 = g6
    agg_h16<64, false, false, false, 1><<<gridN4, TB, 0, stream>>>(
        h0, csr, row_off, nullptr, nullptr, nullptr, nullptr, th, tl, N);
    gemm_mfma<64, 64, true, true, true, 0><<<MB, TB, 0, stream>>>(
        th, tl, wth[5], wtl[5], in_nrm, out_nrm, B6, h1, nullptr, nullptr, N);

    // L7: 64->1 mult-first. t7 = g6@W7 ; out = agg(t7)*r + B7
    gemv64_kernel<<<gridN4, TB, 0, stream>>>(h1, W7, t7, N);
    agg1_kernel<<<(N + 15) / 16, TB, 0, stream>>>(t7, csr, row_off, in_nrm, B7, out, N);
}